// Round 1
// baseline (247.717 us; speedup 1.0000x reference)
//
#include <hip/hip_runtime.h>
#include <cstdint>
#include <cstddef>

// ---------------- types ----------------
typedef __bf16 bf16x8 __attribute__((ext_vector_type(8)));
typedef __bf16 bf16x4 __attribute__((ext_vector_type(4)));
typedef float  f32x4  __attribute__((ext_vector_type(4)));

#define DIMD 1024
#define SEQ  2048
#define NB   2
#define NH   16
#define HD   64
#define QKVN 1536   // 1024 + 2*256

// ---------------- fp32 -> bf16 elementwise (vec4) ----------------
__global__ void cvt_f32_bf16(const float* __restrict__ in, __bf16* __restrict__ out, int n4) {
    int i = blockIdx.x * blockDim.x + threadIdx.x;
    if (i >= n4) return;
    float4 v = reinterpret_cast<const float4*>(in)[i];
    bf16x4 o;
    o[0] = (__bf16)v.x; o[1] = (__bf16)v.y; o[2] = (__bf16)v.z; o[3] = (__bf16)v.w;
    reinterpret_cast<bf16x4*>(out)[i] = o;
}

// ---------------- fp32 [R][C] -> bf16 [C][R] tiled transpose ----------------
__global__ void transpose_cvt(const float* __restrict__ in, __bf16* __restrict__ out, int R, int C) {
    __shared__ float t[32][33];
    int bx = blockIdx.x * 32;   // col tile (C)
    int by = blockIdx.y * 32;   // row tile (R)
    int tx = threadIdx.x, ty = threadIdx.y;   // (32, 8)
#pragma unroll
    for (int i = 0; i < 32; i += 8)
        t[ty + i][tx] = in[(size_t)(by + ty + i) * C + bx + tx];
    __syncthreads();
#pragma unroll
    for (int i = 0; i < 32; i += 8)
        out[(size_t)(bx + ty + i) * R + by + tx] = (__bf16)t[tx][ty + i];
}

// ---------------- bf16 GEMM: C[M,N] = A[M,K] * Bt[N,K]^T + bias ----------------
// 128x128 tile, BK=32, 256 threads = 4 waves (2x2), each wave 64x64 (4x4 frags).
template<int OUT_BF16>
__global__ __launch_bounds__(256) void gemm_bf16(
    const __bf16* __restrict__ A, const __bf16* __restrict__ Bt,
    const float* __restrict__ bias, void* __restrict__ Cout,
    int M, int N, int K)
{
    // pad to 40 elems (80B): 16B-aligned rows, ~2-way (free) bank conflicts
    __shared__ __bf16 Als[128][40];
    __shared__ __bf16 Bls[128][40];
    const int tid  = threadIdx.x;
    const int lane = tid & 63;
    const int wave = tid >> 6;
    const int lo = lane & 15, hi = lane >> 4;
    const int bm = blockIdx.y * 128, bn = blockIdx.x * 128;
    const int wr = (wave >> 1) * 64, wc = (wave & 1) * 64;
    const int sr = tid >> 2;          // staging row 0..63
    const int sk = (tid & 3) * 8;     // staging k offset

    f32x4 acc[4][4] = {};
    const __bf16* Ap = A  + (size_t)(bm + sr) * K + sk;
    const __bf16* Bp = Bt + (size_t)(bn + sr) * K + sk;

    for (int k0 = 0; k0 < K; k0 += 32) {
        __syncthreads();
        *reinterpret_cast<bf16x8*>(&Als[sr][sk])      = *reinterpret_cast<const bf16x8*>(Ap + k0);
        *reinterpret_cast<bf16x8*>(&Als[sr + 64][sk]) = *reinterpret_cast<const bf16x8*>(Ap + (size_t)64 * K + k0);
        *reinterpret_cast<bf16x8*>(&Bls[sr][sk])      = *reinterpret_cast<const bf16x8*>(Bp + k0);
        *reinterpret_cast<bf16x8*>(&Bls[sr + 64][sk]) = *reinterpret_cast<const bf16x8*>(Bp + (size_t)64 * K + k0);
        __syncthreads();

        bf16x8 af[4], bfr[4];
#pragma unroll
        for (int i = 0; i < 4; i++) {
            af[i]  = *reinterpret_cast<const bf16x8*>(&Als[wr + i * 16 + lo][hi * 8]);
            bfr[i] = *reinterpret_cast<const bf16x8*>(&Bls[wc + i * 16 + lo][hi * 8]);
        }
#pragma unroll
        for (int i = 0; i < 4; i++)
#pragma unroll
            for (int j = 0; j < 4; j++)
                acc[i][j] = __builtin_amdgcn_mfma_f32_16x16x32_bf16(af[i], bfr[j], acc[i][j], 0, 0, 0);
    }

#pragma unroll
    for (int j = 0; j < 4; j++) {
        int col = bn + wc + j * 16 + lo;
        float bv = bias[col];
#pragma unroll
        for (int i = 0; i < 4; i++) {
            int row0 = bm + wr + i * 16 + hi * 4;
#pragma unroll
            for (int rr = 0; rr < 4; rr++) {
                float v = acc[i][j][rr] + bv;
                if (OUT_BF16) ((__bf16*)Cout)[(size_t)(row0 + rr) * N + col] = (__bf16)v;
                else          ((float* )Cout)[(size_t)(row0 + rr) * N + col] = v;
            }
        }
    }
}

// ---------------- causal GQA flash attention ----------------
// grid (SEQ/64, NH, NB), 256 threads. Wave w owns q rows [q0+16w, q0+16w+16).
// KV chunk = 32 rows. qkv rows: [q(1024) | k(256) | v(256)], stride 1536, bf16.
__global__ __launch_bounds__(256) void attn_fwd(
    const __bf16* __restrict__ qkv, __bf16* __restrict__ y)
{
    __shared__ __bf16 Vls[32][68];       // 136B rows: b64-aligned stage, 2-way read
    __shared__ __bf16 Pls[4][16][40];    // per-wave P transpose, 80B rows
    const int tid  = threadIdx.x;
    const int wave = tid >> 6, lane = tid & 63;
    const int lo = lane & 15, hi = lane >> 4;
    const int b = blockIdx.z, h = blockIdx.y, kh = h >> 2;
    const int q0 = blockIdx.x * 64;
    const int qw = q0 + wave * 16;
    const float NINF = -__builtin_inff();

    const __bf16* base = qkv + (size_t)b * SEQ * QKVN;
    const __bf16* qp = base + h * HD;
    const __bf16* kp = base + DIMD + kh * HD;
    const __bf16* vp = base + DIMD + 256 + kh * HD;

    // Q fragments (held in registers for the whole K loop)
    bf16x8 aQ0 = *reinterpret_cast<const bf16x8*>(qp + (size_t)(qw + lo) * QKVN + hi * 8);
    bf16x8 aQ1 = *reinterpret_cast<const bf16x8*>(qp + (size_t)(qw + lo) * QKVN + 32 + hi * 8);

    float m[4], ssum[4];
    f32x4 accO[4] = {};
#pragma unroll
    for (int r = 0; r < 4; r++) { m[r] = NINF; ssum[r] = 0.0f; }

    const int vr = tid >> 3, vc = (tid & 7) * 8;
    const int kend = q0 + 64;

    for (int kt = 0; kt < kend; kt += 32) {
        __syncthreads();
        // stage V[kt..kt+32)[0..64) -> LDS (coalesced 16B loads, b64 LDS writes)
        {
            bf16x8 vv = *reinterpret_cast<const bf16x8*>(vp + (size_t)(kt + vr) * QKVN + vc);
            bf16x4 vlo4 = __builtin_shufflevector(vv, vv, 0, 1, 2, 3);
            bf16x4 vhi4 = __builtin_shufflevector(vv, vv, 4, 5, 6, 7);
            *reinterpret_cast<bf16x4*>(&Vls[vr][vc])     = vlo4;
            *reinterpret_cast<bf16x4*>(&Vls[vr][vc + 4]) = vhi4;
        }
        __syncthreads();

        // S = Q K^T for two 16-col subtiles (K frags direct from global; L2-hot)
        f32x4 s0 = {0.f, 0.f, 0.f, 0.f}, s1 = {0.f, 0.f, 0.f, 0.f};
        {
            const __bf16* k0p = kp + (size_t)(kt + lo) * QKVN + hi * 8;
            bf16x8 b0 = *reinterpret_cast<const bf16x8*>(k0p);
            bf16x8 b1 = *reinterpret_cast<const bf16x8*>(k0p + 32);
            s0 = __builtin_amdgcn_mfma_f32_16x16x32_bf16(aQ0, b0, s0, 0, 0, 0);
            s0 = __builtin_amdgcn_mfma_f32_16x16x32_bf16(aQ1, b1, s0, 0, 0, 0);
            const __bf16* k1p = kp + (size_t)(kt + 16 + lo) * QKVN + hi * 8;
            b0 = *reinterpret_cast<const bf16x8*>(k1p);
            b1 = *reinterpret_cast<const bf16x8*>(k1p + 32);
            s1 = __builtin_amdgcn_mfma_f32_16x16x32_bf16(aQ0, b0, s1, 0, 0, 0);
            s1 = __builtin_amdgcn_mfma_f32_16x16x32_bf16(aQ1, b1, s1, 0, 0, 0);
        }

        // scale + causal mask + online softmax (row-reduce over 16-lane group)
#pragma unroll
        for (int r = 0; r < 4; r++) {
            int qg = qw + hi * 4 + r;
            float v0 = (kt + lo      <= qg) ? s0[r] * 0.125f : NINF;
            float v1 = (kt + 16 + lo <= qg) ? s1[r] * 0.125f : NINF;
            s0[r] = v0; s1[r] = v1;
            float t = fmaxf(v0, v1);
            t = fmaxf(t, __shfl_xor(t, 1));
            t = fmaxf(t, __shfl_xor(t, 2));
            t = fmaxf(t, __shfl_xor(t, 4));
            t = fmaxf(t, __shfl_xor(t, 8));
            float mn = fmaxf(m[r], t);
            float sc = __expf(m[r] - mn);   // first iter: exp(-inf - finite) = 0
            m[r] = mn;
            float e0 = __expf(s0[r] - mn);  // masked -> exp(-inf) = 0
            float e1 = __expf(s1[r] - mn);
            float rs = e0 + e1;
            rs += __shfl_xor(rs, 1);
            rs += __shfl_xor(rs, 2);
            rs += __shfl_xor(rs, 4);
            rs += __shfl_xor(rs, 8);
            ssum[r] = ssum[r] * sc + rs;
            accO[0][r] *= sc; accO[1][r] *= sc; accO[2][r] *= sc; accO[3][r] *= sc;
            Pls[wave][hi * 4 + r][lo]      = (__bf16)e0;
            Pls[wave][hi * 4 + r][16 + lo] = (__bf16)e1;
        }

        // P (transposed via LDS) x V
        bf16x8 pA = *reinterpret_cast<const bf16x8*>(&Pls[wave][lo][hi * 8]);
#pragma unroll
        for (int f = 0; f < 4; f++) {
            bf16x8 vB;
#pragma unroll
            for (int e = 0; e < 8; e++) vB[e] = Vls[hi * 8 + e][f * 16 + lo];
            accO[f] = __builtin_amdgcn_mfma_f32_16x16x32_bf16(pA, vB, accO[f], 0, 0, 0);
        }
    }

    // epilogue: normalize and write y[b, q, h*64 + d]
#pragma unroll
    for (int r = 0; r < 4; r++) {
        int q = qw + hi * 4 + r;
        float inv = 1.0f / ssum[r];
#pragma unroll
        for (int f = 0; f < 4; f++) {
            float val = accO[f][r] * inv;
            y[(size_t)(b * SEQ + q) * DIMD + h * HD + f * 16 + lo] = (__bf16)val;
        }
    }
}

// ---------------- launcher ----------------
extern "C" void kernel_launch(void* const* d_in, const int* in_sizes, int n_in,
                              void* d_out, int out_size, void* d_ws, size_t ws_size,
                              hipStream_t stream) {
    const float* x    = (const float*)d_in[0];
    const float* Wqkv = (const float*)d_in[1];
    const float* bqkv = (const float*)d_in[2];
    const float* Wout = (const float*)d_in[3];
    const float* bout = (const float*)d_in[4];
    float* out = (float*)d_out;

    char* ws = (char*)d_ws;
    __bf16* xb    = (__bf16*)(ws);                          // 8 MB  (x bf16; later reused as y)
    __bf16* wqkvT = (__bf16*)(ws + ((size_t)8  << 20));     // 3 MB  [1536][1024]
    __bf16* woutT = (__bf16*)(ws + ((size_t)11 << 20));     // 2 MB  [1024][1024]
    __bf16* qkvb  = (__bf16*)(ws + ((size_t)13 << 20));     // 12 MB [4096][1536]
    __bf16* yb    = xb;                                     // alias: xb dead after GEMM1

    const int M = NB * SEQ;   // 4096

    cvt_f32_bf16<<<(M * DIMD / 4 + 255) / 256, 256, 0, stream>>>(x, xb, M * DIMD / 4);
    transpose_cvt<<<dim3(QKVN / 32, DIMD / 32), dim3(32, 8), 0, stream>>>(Wqkv, wqkvT, DIMD, QKVN);
    transpose_cvt<<<dim3(DIMD / 32, DIMD / 32), dim3(32, 8), 0, stream>>>(Wout, woutT, DIMD, DIMD);

    gemm_bf16<1><<<dim3(QKVN / 128, M / 128), 256, 0, stream>>>(xb, wqkvT, bqkv, qkvb, M, QKVN, DIMD);

    attn_fwd<<<dim3(SEQ / 64, NH, NB), 256, 0, stream>>>(qkvb, yb);

    gemm_bf16<0><<<dim3(DIMD / 128, M / 128), 256, 0, stream>>>(yb, woutT, bout, out, M, DIMD, DIMD);
}

// Round 2
// 190.997 us; speedup vs baseline: 1.2970x; 1.2970x over previous
//
#include <hip/hip_runtime.h>
#include <cstdint>
#include <cstddef>

// ---------------- types ----------------
typedef __bf16 bf16x8 __attribute__((ext_vector_type(8)));
typedef __bf16 bf16x4 __attribute__((ext_vector_type(4)));
typedef float  f32x4  __attribute__((ext_vector_type(4)));

#define DIMD 1024
#define SEQ  2048
#define NB   2
#define NH   16
#define HD   64
#define QKVN 1536   // 1024 + 2*256

// async global->LDS (16B per lane, wave-uniform LDS base)
typedef __attribute__((address_space(1))) const void* as1_cvp;
typedef __attribute__((address_space(3))) void* as3_vp;
#define GLL16(g, l) __builtin_amdgcn_global_load_lds((as1_cvp)(const void*)(g), (as3_vp)(void*)(l), 16, 0, 0)

// ---------------- fp32 -> bf16 elementwise (vec4) ----------------
__global__ void cvt_f32_bf16(const float* __restrict__ in, __bf16* __restrict__ out, int n4) {
    int i = blockIdx.x * blockDim.x + threadIdx.x;
    if (i >= n4) return;
    float4 v = reinterpret_cast<const float4*>(in)[i];
    bf16x4 o;
    o[0] = (__bf16)v.x; o[1] = (__bf16)v.y; o[2] = (__bf16)v.z; o[3] = (__bf16)v.w;
    reinterpret_cast<bf16x4*>(out)[i] = o;
}

// ---------------- fp32 [R][C] -> bf16 [C][R] tiled transpose ----------------
__global__ void transpose_cvt(const float* __restrict__ in, __bf16* __restrict__ out, int R, int C) {
    __shared__ float t[32][33];
    int bx = blockIdx.x * 32;
    int by = blockIdx.y * 32;
    int tx = threadIdx.x, ty = threadIdx.y;   // (32, 8)
#pragma unroll
    for (int i = 0; i < 32; i += 8)
        t[ty + i][tx] = in[(size_t)(by + ty + i) * C + bx + tx];
    __syncthreads();
#pragma unroll
    for (int i = 0; i < 32; i += 8)
        out[(size_t)(bx + ty + i) * R + by + tx] = (__bf16)t[tx][ty + i];
}

// ---------------- bf16 GEMM (m97 structure): C[M,N] = A[M,K]*Bt[N,K]^T + bias ----
// 128x128 tile, BK=32, 4 waves (2x2), wave 64x64. Linear LDS + global_load_lds.
template<int OUT_BF16>
__global__ __launch_bounds__(256) void gemm_bf16(
    const __bf16* __restrict__ A, const __bf16* __restrict__ Bt,
    const float* __restrict__ bias, void* __restrict__ Cout,
    int M, int N, int K)
{
    __shared__ __bf16 Als[128 * 32];   // linear: row*32 + k  (64B rows -> conflict-free b128)
    __shared__ __bf16 Bls[128 * 32];
    const int tid  = threadIdx.x;
    const int lane = tid & 63;
    const int wave = tid >> 6;
    const int lo = lane & 15, hi = lane >> 4;
    const int bm = blockIdx.y * 128, bn = blockIdx.x * 128;
    const int wr = (wave >> 1) * 64, wc = (wave & 1) * 64;

    // staging: wave w owns rows [w*32, w*32+32) of both tiles, 2 gll-instrs each
    const __bf16* gA = A  + (size_t)(bm + wave * 32 + (lane >> 2)) * K + (lane & 3) * 8;
    const __bf16* gB = Bt + (size_t)(bn + wave * 32 + (lane >> 2)) * K + (lane & 3) * 8;
    __bf16* lA = &Als[wave * 32 * 32];
    __bf16* lB = &Bls[wave * 32 * 32];

    f32x4 acc[4][4] = {};

    for (int k0 = 0; k0 < K; k0 += 32) {
        __syncthreads();
        GLL16(gA + k0,                  lA);
        GLL16(gA + k0 + (size_t)16 * K, lA + 512);
        GLL16(gB + k0,                  lB);
        GLL16(gB + k0 + (size_t)16 * K, lB + 512);
        __syncthreads();   // drains vmcnt -> LDS visible

        bf16x8 af[4], bfr[4];
#pragma unroll
        for (int i = 0; i < 4; i++) {
            af[i]  = *reinterpret_cast<const bf16x8*>(&Als[(wr + i * 16 + lo) * 32 + hi * 8]);
            bfr[i] = *reinterpret_cast<const bf16x8*>(&Bls[(wc + i * 16 + lo) * 32 + hi * 8]);
        }
#pragma unroll
        for (int i = 0; i < 4; i++)
#pragma unroll
            for (int j = 0; j < 4; j++)
                acc[i][j] = __builtin_amdgcn_mfma_f32_16x16x32_bf16(af[i], bfr[j], acc[i][j], 0, 0, 0);
    }

#pragma unroll
    for (int j = 0; j < 4; j++) {
        int col = bn + wc + j * 16 + lo;
        float bv = bias[col];
#pragma unroll
        for (int i = 0; i < 4; i++) {
            int row0 = bm + wr + i * 16 + hi * 4;
#pragma unroll
            for (int rr = 0; rr < 4; rr++) {
                float v = acc[i][j][rr] + bv;
                if (OUT_BF16) ((__bf16*)Cout)[(size_t)(row0 + rr) * N + col] = (__bf16)v;
                else          ((float* )Cout)[(size_t)(row0 + rr) * N + col] = v;
            }
        }
    }
}

// ---------------- causal GQA flash attention ----------------
// grid (16, NH, NB): block p handles q-tiles {p, 31-p} (balanced: 33 chunk-64s).
// 4 waves x 16 q-rows, KV chunk = 64, V staged transposed in LDS.
__global__ __launch_bounds__(256) void attn_fwd(
    const __bf16* __restrict__ qkv, __bf16* __restrict__ y)
{
    __shared__ __bf16 Vt[64][72];        // V^T: [d][k], 144B rows (16B-aligned, conflict-free b128)
    __shared__ __bf16 Pls[4][16][72];    // per-wave P, 144B rows
    const int tid  = threadIdx.x;
    const int wave = tid >> 6, lane = tid & 63;
    const int lo = lane & 15, hi = lane >> 4;
    const int b = blockIdx.z, h = blockIdx.y, kh = h >> 2;
    const float NINF = -__builtin_inff();

    const __bf16* base = qkv + (size_t)b * SEQ * QKVN;
    const __bf16* qp = base + h * HD;
    const __bf16* kp = base + DIMD + kh * HD;
    const __bf16* vp = base + DIMD + 256 + kh * HD;

    const int vr = tid >> 2;           // 0..63 (k row within chunk)
    const int vc = (tid & 3) * 16;     // 0,16,32,48 (d base)

    for (int t = 0; t < 2; ++t) {
        const int tile = (t == 0) ? (int)blockIdx.x : 31 - (int)blockIdx.x;
        const int q0 = tile * 64;
        const int qw = q0 + wave * 16;

        bf16x8 aQ0 = *reinterpret_cast<const bf16x8*>(qp + (size_t)(qw + lo) * QKVN + hi * 8);
        bf16x8 aQ1 = *reinterpret_cast<const bf16x8*>(qp + (size_t)(qw + lo) * QKVN + 32 + hi * 8);

        float m[4], ssum[4];
        f32x4 accO[4] = {};
#pragma unroll
        for (int r = 0; r < 4; r++) { m[r] = NINF; ssum[r] = 0.0f; }

        for (int kt = 0; kt < q0 + 64; kt += 64) {
            __syncthreads();
            // stage V[kt..kt+64)[0..64) transposed -> Vt[d][k]
            {
                const __bf16* vsrc = vp + (size_t)(kt + vr) * QKVN + vc;
                bf16x8 v0 = *reinterpret_cast<const bf16x8*>(vsrc);
                bf16x8 v1 = *reinterpret_cast<const bf16x8*>(vsrc + 8);
#pragma unroll
                for (int e = 0; e < 8; e++) {
                    Vt[vc + e][vr]     = v0[e];
                    Vt[vc + 8 + e][vr] = v1[e];
                }
            }
            __syncthreads();

            // S = Q K^T : 4 subtiles of 16 keys (K frags direct from global; L2-hot)
            f32x4 s[4];
#pragma unroll
            for (int j = 0; j < 4; j++) {
                const __bf16* kpp = kp + (size_t)(kt + j * 16 + lo) * QKVN + hi * 8;
                bf16x8 b0 = *reinterpret_cast<const bf16x8*>(kpp);
                bf16x8 b1 = *reinterpret_cast<const bf16x8*>(kpp + 32);
                f32x4 z = {0.f, 0.f, 0.f, 0.f};
                z = __builtin_amdgcn_mfma_f32_16x16x32_bf16(aQ0, b0, z, 0, 0, 0);
                z = __builtin_amdgcn_mfma_f32_16x16x32_bf16(aQ1, b1, z, 0, 0, 0);
                s[j] = z;
            }

            // scale + causal mask + online softmax (reduce over 16-lane group)
#pragma unroll
            for (int r = 0; r < 4; r++) {
                int qg = qw + hi * 4 + r;
                float v0 = (kt + lo      <= qg) ? s[0][r] * 0.125f : NINF;
                float v1 = (kt + 16 + lo <= qg) ? s[1][r] * 0.125f : NINF;
                float v2 = (kt + 32 + lo <= qg) ? s[2][r] * 0.125f : NINF;
                float v3 = (kt + 48 + lo <= qg) ? s[3][r] * 0.125f : NINF;
                float mx = fmaxf(fmaxf(v0, v1), fmaxf(v2, v3));
                mx = fmaxf(mx, __shfl_xor(mx, 1));
                mx = fmaxf(mx, __shfl_xor(mx, 2));
                mx = fmaxf(mx, __shfl_xor(mx, 4));
                mx = fmaxf(mx, __shfl_xor(mx, 8));
                float mn = fmaxf(m[r], mx);
                float sc = __expf(m[r] - mn);   // first chunk: exp(-inf - finite) = 0
                m[r] = mn;
                float e0 = __expf(v0 - mn);
                float e1 = __expf(v1 - mn);
                float e2 = __expf(v2 - mn);
                float e3 = __expf(v3 - mn);
                float rs = (e0 + e1) + (e2 + e3);
                rs += __shfl_xor(rs, 1);
                rs += __shfl_xor(rs, 2);
                rs += __shfl_xor(rs, 4);
                rs += __shfl_xor(rs, 8);
                ssum[r] = ssum[r] * sc + rs;
                accO[0][r] *= sc; accO[1][r] *= sc; accO[2][r] *= sc; accO[3][r] *= sc;
                Pls[wave][hi * 4 + r][lo]      = (__bf16)e0;
                Pls[wave][hi * 4 + r][16 + lo] = (__bf16)e1;
                Pls[wave][hi * 4 + r][32 + lo] = (__bf16)e2;
                Pls[wave][hi * 4 + r][48 + lo] = (__bf16)e3;
            }

            // P x V : A-frag from Pls (own wave), B-frag = contiguous b128 from Vt
#pragma unroll
            for (int ks = 0; ks < 2; ks++) {
                bf16x8 pA = *reinterpret_cast<const bf16x8*>(&Pls[wave][lo][ks * 32 + hi * 8]);
#pragma unroll
                for (int f = 0; f < 4; f++) {
                    bf16x8 vB = *reinterpret_cast<const bf16x8*>(&Vt[f * 16 + lo][ks * 32 + hi * 8]);
                    accO[f] = __builtin_amdgcn_mfma_f32_16x16x32_bf16(pA, vB, accO[f], 0, 0, 0);
                }
            }
        }

        // epilogue: normalize, write y[b, q, h*64 + d]
#pragma unroll
        for (int r = 0; r < 4; r++) {
            int q = qw + hi * 4 + r;
            float inv = 1.0f / ssum[r];
#pragma unroll
            for (int f = 0; f < 4; f++) {
                float val = accO[f][r] * inv;
                y[(size_t)(b * SEQ + q) * DIMD + h * HD + f * 16 + lo] = (__bf16)val;
            }
        }
    }
}

// ---------------- launcher ----------------
extern "C" void kernel_launch(void* const* d_in, const int* in_sizes, int n_in,
                              void* d_out, int out_size, void* d_ws, size_t ws_size,
                              hipStream_t stream) {
    const float* x    = (const float*)d_in[0];
    const float* Wqkv = (const float*)d_in[1];
    const float* bqkv = (const float*)d_in[2];
    const float* Wout = (const float*)d_in[3];
    const float* bout = (const float*)d_in[4];
    float* out = (float*)d_out;

    char* ws = (char*)d_ws;
    __bf16* xb    = (__bf16*)(ws);                          // 8 MB  (x bf16; later reused as y)
    __bf16* wqkvT = (__bf16*)(ws + ((size_t)8  << 20));     // 3 MB  [1536][1024]
    __bf16* woutT = (__bf16*)(ws + ((size_t)11 << 20));     // 2 MB  [1024][1024]
    __bf16* qkvb  = (__bf16*)(ws + ((size_t)13 << 20));     // 12 MB [4096][1536]
    __bf16* yb    = xb;                                     // alias: xb dead after GEMM1

    const int M = NB * SEQ;   // 4096

    cvt_f32_bf16<<<(M * DIMD / 4 + 255) / 256, 256, 0, stream>>>(x, xb, M * DIMD / 4);
    transpose_cvt<<<dim3(QKVN / 32, DIMD / 32), dim3(32, 8), 0, stream>>>(Wqkv, wqkvT, DIMD, QKVN);
    transpose_cvt<<<dim3(DIMD / 32, DIMD / 32), dim3(32, 8), 0, stream>>>(Wout, woutT, DIMD, DIMD);

    gemm_bf16<1><<<dim3(QKVN / 128, M / 128), 256, 0, stream>>>(xb, wqkvT, bqkv, qkvb, M, QKVN, DIMD);

    attn_fwd<<<dim3(16, NH, NB), 256, 0, stream>>>(qkvb, yb);

    gemm_bf16<0><<<dim3(DIMD / 128, M / 128), 256, 0, stream>>>(yb, woutT, bout, out, M, DIMD, DIMD);
}